// Round 5
// baseline (2428.206 us; speedup 1.0000x reference)
//
#include <hip/hip_runtime.h>
#include <math.h>

// Problem constants (from reference)
constexpr int NE  = 200000;  // edges
constexpr int ND  = 120;     // node feature dim = 32 + 48 + 40
constexpr int EPB = 128;     // edges per 256-thread block (2 lanes per edge)

__device__ __forceinline__ float silu_f(float x) { return x / (1.0f + __expf(-x)); }

// 2-lanes-per-edge: lane pair (2t,2t+1) shares edge t. 64-wide hidden vectors
// split 32/32 across the pair (half = tid&1), TP accumulator split 16/16.
// Pair exchange via LDS columns (same wave -> in-order LDS, no s_barrier) and
// __shfl_xor(.,1). scr = 64 rows x 128 edges x 4B = 32 KB -> 4 blocks/CU.
__global__ __launch_bounds__(256, 4) void fused_edge_kernel(
    const float* __restrict__ nodes,
    const int*   __restrict__ src,
    const int*   __restrict__ dst,
    const int*   __restrict__ batch_vec,
    const float* __restrict__ cell,
    const float* __restrict__ edge_shift,
    const float* __restrict__ pos,
    const float* __restrict__ angles,
    const float* __restrict__ cr_min,
    const float* __restrict__ cr_max,
    const float* __restrict__ W0,
    const float* __restrict__ W1,
    const float* __restrict__ W2,
    const float* __restrict__ ln_g,
    const float* __restrict__ ln_b,
    const float* __restrict__ rw1,
    const float* __restrict__ rb1,
    const float* __restrict__ rw2,
    const float* __restrict__ rb2,
    const float* __restrict__ mw1,
    const float* __restrict__ mb1,
    const float* __restrict__ mw2,
    const float* __restrict__ mb2,
    const float* __restrict__ ow,
    const float* __restrict__ ob,
    float* __restrict__ out)
{
    __shared__ float scr[64 * EPB];  // 32 KB
    const int tid  = threadIdx.x;
    const int el   = tid >> 1;       // edge slot within block [0,128)
    const int half = tid & 1;        // which 32-half of 64-wide vectors
    const int j0   = half * 32;      // offset into 64-wide dims
    const int w0i  = half * 16;      // offset into 32-wide LN dim
    const int eg   = blockIdx.x * EPB + el;
    const int e    = (eg < NE) ? eg : (NE - 1);  // clamp tail (no early return)

    const int is = src[e];
    const int id = dst[e];
    const float* __restrict__ x1 = nodes + (size_t)is * ND;
    const float* __restrict__ x2 = nodes + (size_t)id * ND;

    // ---------------- geometry: dist (duplicated in both pair lanes) --------
    const int bg = batch_vec[is];
    const float* C = cell + bg * 9;
    const float sh0 = edge_shift[e * 3 + 0];
    const float sh1 = edge_shift[e * 3 + 1];
    const float sh2 = edge_shift[e * 3 + 2];
    const float rx = pos[id * 3 + 0] - pos[is * 3 + 0] + sh0 * C[0] + sh1 * C[3] + sh2 * C[6];
    const float ry = pos[id * 3 + 1] - pos[is * 3 + 1] + sh0 * C[1] + sh1 * C[4] + sh2 * C[7];
    const float rz = pos[id * 3 + 2] - pos[is * 3 + 2] + sh0 * C[2] + sh1 * C[5] + sh2 * C[8];
    const float dist = sqrtf(rx * rx + ry * ry + rz * rz);

    // ---------------- radial layer 1: this lane's 32 of h1 ------------------
    {
        float h1[32];
        #pragma unroll
        for (int jj = 0; jj < 32; ++jj) h1[jj] = rb1[j0 + jj];
        #pragma unroll 1
        for (int i = 0; i < 64; ++i) {
            const float dd = dist - (5.0f / 63.0f) * (float)i;
            const float r = __expf(-10.0f * dd * dd);
            const float* __restrict__ wp = rw1 + i * 64 + j0;
            #pragma unroll
            for (int jj = 0; jj < 32; ++jj) h1[jj] = fmaf(r, wp[jj], h1[jj]);
        }
        // publish silu(h1) rows [j0, j0+32) for the pair
        #pragma unroll
        for (int jj = 0; jj < 32; ++jj) scr[(j0 + jj) * EPB + el] = silu_f(h1[jj]);
    }
    __builtin_amdgcn_wave_barrier();

    // ---------------- radial layer 2: emb (this lane's 32) ------------------
    float emb[32];
    #pragma unroll
    for (int m = 0; m < 32; ++m) emb[m] = rb2[j0 + m];
    #pragma unroll 1
    for (int k = 0; k < 64; ++k) {            // rolled: keeps LDS read ordered
        const float hk = scr[k * EPB + el];
        const float* __restrict__ wp = rw2 + k * 64 + j0;
        #pragma unroll
        for (int m = 0; m < 32; ++m) emb[m] = fmaf(hk, wp[m], emb[m]);
    }
    __builtin_amdgcn_wave_barrier();
    #pragma unroll
    for (int m = 0; m < 32; ++m) scr[(j0 + m) * EPB + el] = emb[m];
    __builtin_amdgcn_wave_barrier();

    // ---------------- MLP layer-1 partial: h2 (this lane's 32) --------------
    float h2[32];
    #pragma unroll
    for (int jl = 0; jl < 32; ++jl) h2[jl] = mb1[j0 + jl];
    #pragma unroll 1
    for (int i = 0; i < 64; ++i) {
        const float ei = scr[i * EPB + el];
        const float* __restrict__ wp = mw1 + (32 + i) * 64 + j0;
        #pragma unroll
        for (int jl = 0; jl < 32; ++jl) h2[jl] = fmaf(ei, wp[jl], h2[jl]);
    }
    {
        const float a  = angles[e];
        const float cm = cr_min[e];
        const float cx = cr_max[e];
        const float* __restrict__ wa = mw1 + 96 * 64 + j0;
        const float* __restrict__ wb = mw1 + 97 * 64 + j0;
        const float* __restrict__ wc = mw1 + 98 * 64 + j0;
        #pragma unroll
        for (int jl = 0; jl < 32; ++jl)
            h2[jl] += a * wa[jl] + cm * wb[jl] + cx * wc[jl];
    }
    __builtin_amdgcn_wave_barrier();

    // ---------------- tensor product -> this lane's 16 of acc[32] -----------
    float acc[16];
    #pragma unroll
    for (int wl = 0; wl < 16; ++wl) acc[wl] = 0.0f;

    { // L0 x L0 -> W0 (32,32,32)
        float b0[32];
        #pragma unroll
        for (int q = 0; q < 8; ++q) {
            const float4 f = *reinterpret_cast<const float4*>(x2 + 4 * q);
            b0[4 * q + 0] = f.x; b0[4 * q + 1] = f.y;
            b0[4 * q + 2] = f.z; b0[4 * q + 3] = f.w;
        }
        #pragma unroll 1
        for (int u = 0; u < 32; ++u) {
            const float a = x1[u];
            const float* __restrict__ wp = W0 + u * 1024 + w0i;  // + v*32 + wl
            #pragma unroll
            for (int v = 0; v < 32; ++v) {
                const float p = a * b0[v];
                #pragma unroll
                for (int wl = 0; wl < 16; ++wl)
                    acc[wl] = fmaf(p, wp[v * 32 + wl], acc[wl]);
            }
        }
    }
    { // L1 x L1 (dot over 3) -> W1 (16,16,32), * 1/sqrt(3)
        float bv[48];
        #pragma unroll
        for (int q = 0; q < 12; ++q) {
            const float4 f = *reinterpret_cast<const float4*>(x2 + 32 + 4 * q);
            bv[4 * q + 0] = f.x; bv[4 * q + 1] = f.y;
            bv[4 * q + 2] = f.z; bv[4 * q + 3] = f.w;
        }
        const float c1 = 0.57735026918962576f; // 1/sqrt(3)
        #pragma unroll 1
        for (int u = 0; u < 16; ++u) {
            const float a0 = x1[32 + 3 * u + 0];
            const float a1 = x1[32 + 3 * u + 1];
            const float a2 = x1[32 + 3 * u + 2];
            const float* __restrict__ wp = W1 + u * 512 + w0i;
            #pragma unroll
            for (int v = 0; v < 16; ++v) {
                const float d = a0 * bv[3 * v + 0] + a1 * bv[3 * v + 1] + a2 * bv[3 * v + 2];
                const float p = d * c1;
                #pragma unroll
                for (int wl = 0; wl < 16; ++wl)
                    acc[wl] = fmaf(p, wp[v * 32 + wl], acc[wl]);
            }
        }
    }
    { // L2 x L2 (dot over 5) -> W2 (8,8,32), * 1/sqrt(5)
        float bt[40];
        #pragma unroll
        for (int q = 0; q < 10; ++q) {
            const float4 f = *reinterpret_cast<const float4*>(x2 + 80 + 4 * q);
            bt[4 * q + 0] = f.x; bt[4 * q + 1] = f.y;
            bt[4 * q + 2] = f.z; bt[4 * q + 3] = f.w;
        }
        const float c2 = 0.44721359549995794f; // 1/sqrt(5)
        #pragma unroll 1
        for (int u = 0; u < 8; ++u) {
            const float a0 = x1[80 + 5 * u + 0];
            const float a1 = x1[80 + 5 * u + 1];
            const float a2 = x1[80 + 5 * u + 2];
            const float a3 = x1[80 + 5 * u + 3];
            const float a4 = x1[80 + 5 * u + 4];
            const float* __restrict__ wp = W2 + u * 256 + w0i;
            #pragma unroll
            for (int v = 0; v < 8; ++v) {
                const float d = a0 * bt[5 * v + 0] + a1 * bt[5 * v + 1] + a2 * bt[5 * v + 2]
                              + a3 * bt[5 * v + 3] + a4 * bt[5 * v + 4];
                const float p = d * c2;
                #pragma unroll
                for (int wl = 0; wl < 16; ++wl)
                    acc[wl] = fmaf(p, wp[v * 32 + wl], acc[wl]);
            }
        }
    }

    // ---------------- scale + layernorm (pair-reduced stats) ----------------
    const float tp_scale = 0.027277236685610633f; // 1/sqrt(32*32 + 16*16 + 8*8)
    #pragma unroll
    for (int wl = 0; wl < 16; ++wl) acc[wl] *= tp_scale;
    float s = 0.0f;
    #pragma unroll
    for (int wl = 0; wl < 16; ++wl) s += acc[wl];
    s += __shfl_xor(s, 1);
    const float mu = s * (1.0f / 32.0f);
    float vv = 0.0f;
    #pragma unroll
    for (int wl = 0; wl < 16; ++wl) { const float d = acc[wl] - mu; vv = fmaf(d, d, vv); }
    vv += __shfl_xor(vv, 1);
    const float rstd = rsqrtf(vv * (1.0f / 32.0f) + 1e-5f);
    #pragma unroll
    for (int wl = 0; wl < 16; ++wl)
        scr[(w0i + wl) * EPB + el] =
            (acc[wl] - mu) * rstd * ln_g[w0i + wl] + ln_b[w0i + wl];
    __builtin_amdgcn_wave_barrier();

    // ---------------- MLP layer-1: h2 += mn @ mw1[0:32], then silu ----------
    #pragma unroll 1
    for (int i = 0; i < 32; ++i) {
        const float mi = scr[i * EPB + el];
        const float* __restrict__ wp = mw1 + i * 64 + j0;
        #pragma unroll
        for (int jl = 0; jl < 32; ++jl) h2[jl] = fmaf(mi, wp[jl], h2[jl]);
    }
    __builtin_amdgcn_wave_barrier();
    #pragma unroll
    for (int jj = 0; jj < 32; ++jj) scr[(j0 + jj) * EPB + el] = silu_f(h2[jj]);
    __builtin_amdgcn_wave_barrier();

    // ---------------- MLP layer-2 + out -------------------------------------
    float h3[32];
    #pragma unroll
    for (int jl = 0; jl < 32; ++jl) h3[jl] = mb2[j0 + jl];
    #pragma unroll 1
    for (int k = 0; k < 64; ++k) {
        const float hk = scr[k * EPB + el];
        const float* __restrict__ wp = mw2 + k * 64 + j0;
        #pragma unroll
        for (int jl = 0; jl < 32; ++jl) h3[jl] = fmaf(hk, wp[jl], h3[jl]);
    }
    float r = 0.0f;
    #pragma unroll
    for (int jl = 0; jl < 32; ++jl) r = fmaf(silu_f(h3[jl]), ow[j0 + jl], r);
    r += __shfl_xor(r, 1);
    if (half == 0 && eg < NE) out[eg] = r + ob[0];
}

extern "C" void kernel_launch(void* const* d_in, const int* in_sizes, int n_in,
                              void* d_out, int out_size, void* d_ws, size_t ws_size,
                              hipStream_t stream) {
    const float* nodes      = (const float*)d_in[0];
    const int*   src        = (const int*)  d_in[1];
    const int*   dst        = (const int*)  d_in[2];
    const int*   batch_vec  = (const int*)  d_in[3];
    const float* cell       = (const float*)d_in[4];
    const float* edge_shift = (const float*)d_in[5];
    const float* pos        = (const float*)d_in[6];
    const float* angles     = (const float*)d_in[7];
    const float* cr_min     = (const float*)d_in[8];
    const float* cr_max     = (const float*)d_in[9];
    const float* W0         = (const float*)d_in[10];
    const float* W1         = (const float*)d_in[11];
    const float* W2         = (const float*)d_in[12];
    const float* ln_g       = (const float*)d_in[13];
    const float* ln_b       = (const float*)d_in[14];
    const float* rw1        = (const float*)d_in[15];
    const float* rb1        = (const float*)d_in[16];
    const float* rw2        = (const float*)d_in[17];
    const float* rb2        = (const float*)d_in[18];
    const float* mw1        = (const float*)d_in[19];
    const float* mb1        = (const float*)d_in[20];
    const float* mw2        = (const float*)d_in[21];
    const float* mb2        = (const float*)d_in[22];
    const float* ow         = (const float*)d_in[23];
    const float* ob         = (const float*)d_in[24];
    float* out = (float*)d_out;

    const dim3 grid((NE + EPB - 1) / EPB);
    const dim3 block(256);
    hipLaunchKernelGGL(fused_edge_kernel, grid, block, 0, stream,
                       nodes, src, dst, batch_vec, cell, edge_shift, pos,
                       angles, cr_min, cr_max, W0, W1, W2, ln_g, ln_b,
                       rw1, rb1, rw2, rb2, mw1, mb1, mw2, mb2, ow, ob, out);
}

// Round 7
// 974.341 us; speedup vs baseline: 2.4922x; 2.4922x over previous
//
#include <hip/hip_runtime.h>
#include <math.h>

// Problem constants (from reference)
constexpr int NE = 200000;   // edges
constexpr int ND = 120;      // node feature dim = 32 + 48 + 40
constexpr int BS = 128;      // threads per block, thread-per-edge

__device__ __forceinline__ float silu_f(float x) { return x / (1.0f + __expf(-x)); }

// Round-4 skeleton (thread-per-edge, wave-uniform weight rows -> scalar
// broadcast loads) + latency fixes: 32 KB LDS (5 blocks/CU = 10 waves/CU)
// and unroll-2 outer weight loops (2 independent load->FMA chains).
__global__ __launch_bounds__(BS, 3) void fused_edge_kernel(
    const float* __restrict__ nodes,
    const int*   __restrict__ src,
    const int*   __restrict__ dst,
    const int*   __restrict__ batch_vec,
    const float* __restrict__ cell,
    const float* __restrict__ edge_shift,
    const float* __restrict__ pos,
    const float* __restrict__ angles,
    const float* __restrict__ cr_min,
    const float* __restrict__ cr_max,
    const float* __restrict__ W0,
    const float* __restrict__ W1,
    const float* __restrict__ W2,
    const float* __restrict__ ln_g,
    const float* __restrict__ ln_b,
    const float* __restrict__ rw1,
    const float* __restrict__ rb1,
    const float* __restrict__ rw2,
    const float* __restrict__ rb2,
    const float* __restrict__ mw1,
    const float* __restrict__ mb1,
    const float* __restrict__ mw2,
    const float* __restrict__ mb2,
    const float* __restrict__ ow,
    const float* __restrict__ ob,
    float* __restrict__ out)
{
    // k-major scratch: thread t's slot k at scr[k*BS + t]; 64 lanes hit 32
    // banks 2-way (free). 32 KB -> 5 blocks/CU.
    __shared__ float scr[64 * BS];
    const int tid = threadIdx.x;
    const int e = blockIdx.x * BS + tid;
    if (e >= NE) return;

    const int is = src[e];
    const int id = dst[e];
    const float* __restrict__ x1 = nodes + (size_t)is * ND;
    const float* __restrict__ x2 = nodes + (size_t)id * ND;

    // ---------------- geometry: dist ----------------
    const int bg = batch_vec[is];
    const float* C = cell + bg * 9;
    const float sh0 = edge_shift[e * 3 + 0];
    const float sh1 = edge_shift[e * 3 + 1];
    const float sh2 = edge_shift[e * 3 + 2];
    const float rx = pos[id * 3 + 0] - pos[is * 3 + 0] + sh0 * C[0] + sh1 * C[3] + sh2 * C[6];
    const float ry = pos[id * 3 + 1] - pos[is * 3 + 1] + sh0 * C[1] + sh1 * C[4] + sh2 * C[7];
    const float rz = pos[id * 3 + 2] - pos[is * 3 + 2] + sh0 * C[2] + sh1 * C[5] + sh2 * C[8];
    const float dist = sqrtf(rx * rx + ry * ry + rz * rz);

    // ---------------- radial layer 1: h1 = silu(rbf @ rw1 + rb1) ----------------
    {
        float h1[64];
        #pragma unroll
        for (int j = 0; j < 64; ++j) h1[j] = rb1[j];
        #pragma unroll 2
        for (int i = 0; i < 64; ++i) {
            const float dd = dist - (5.0f / 63.0f) * (float)i;
            const float r = __expf(-10.0f * dd * dd);
            const float* __restrict__ wp = rw1 + i * 64;
            #pragma unroll
            for (int j = 0; j < 64; ++j) h1[j] = fmaf(r, wp[j], h1[j]);
        }
        #pragma unroll
        for (int j = 0; j < 64; ++j) {
            const float x = h1[j];
            scr[j * BS + tid] = x / (1.0f + __expf(-x));   // silu -> LDS
        }
    }

    // ---------------- radial layer 2: emb = h1 @ rw2 + rb2 ----------------
    {
        float emb[64];
        #pragma unroll
        for (int j = 0; j < 64; ++j) emb[j] = rb2[j];
        #pragma unroll 2
        for (int k = 0; k < 64; ++k) {
            const float hk = scr[k * BS + tid];
            const float* __restrict__ wp = rw2 + k * 64;
            #pragma unroll
            for (int j = 0; j < 64; ++j) emb[j] = fmaf(hk, wp[j], emb[j]);
        }
        #pragma unroll
        for (int j = 0; j < 64; ++j) scr[j * BS + tid] = emb[j]; // emb -> LDS
    }

    // ---------------- MLP layer-1 partial: h2 = mb1 + emb@mw1[32:96] + scalars ----------------
    float h2[64];
    #pragma unroll
    for (int j = 0; j < 64; ++j) h2[j] = mb1[j];
    #pragma unroll 2
    for (int i = 0; i < 64; ++i) {
        const float ei = scr[i * BS + tid];
        const float* __restrict__ wp = mw1 + (32 + i) * 64;
        #pragma unroll
        for (int j = 0; j < 64; ++j) h2[j] = fmaf(ei, wp[j], h2[j]);
    }
    {
        const float a  = angles[e];
        const float cm = cr_min[e];
        const float cx = cr_max[e];
        const float* __restrict__ wa = mw1 + 96 * 64;
        const float* __restrict__ wb = mw1 + 97 * 64;
        const float* __restrict__ wc = mw1 + 98 * 64;
        #pragma unroll
        for (int j = 0; j < 64; ++j)
            h2[j] += a * wa[j] + cm * wb[j] + cx * wc[j];
    }

    // ---------------- tensor product -> acc[32] ----------------
    float acc[32];
    #pragma unroll
    for (int w = 0; w < 32; ++w) acc[w] = 0.0f;

    { // L0 x L0 -> W0 (32,32,32)
        float b0[32];
        #pragma unroll
        for (int q = 0; q < 8; ++q) {
            const float4 f = *reinterpret_cast<const float4*>(x2 + 4 * q);
            b0[4 * q + 0] = f.x; b0[4 * q + 1] = f.y;
            b0[4 * q + 2] = f.z; b0[4 * q + 3] = f.w;
        }
        #pragma unroll 2
        for (int u = 0; u < 32; ++u) {
            const float a = x1[u];
            const float* __restrict__ wp = W0 + u * 1024;
            #pragma unroll
            for (int v = 0; v < 32; ++v) {
                const float p = a * b0[v];
                #pragma unroll
                for (int w = 0; w < 32; ++w)
                    acc[w] = fmaf(p, wp[v * 32 + w], acc[w]);
            }
        }
    }
    { // L1 x L1 (dot over 3) -> W1 (16,16,32), * 1/sqrt(3)
        float bv[48];
        #pragma unroll
        for (int q = 0; q < 12; ++q) {
            const float4 f = *reinterpret_cast<const float4*>(x2 + 32 + 4 * q);
            bv[4 * q + 0] = f.x; bv[4 * q + 1] = f.y;
            bv[4 * q + 2] = f.z; bv[4 * q + 3] = f.w;
        }
        const float c1 = 0.57735026918962576f; // 1/sqrt(3)
        #pragma unroll 2
        for (int u = 0; u < 16; ++u) {
            const float a0 = x1[32 + 3 * u + 0];
            const float a1 = x1[32 + 3 * u + 1];
            const float a2 = x1[32 + 3 * u + 2];
            const float* __restrict__ wp = W1 + u * 512;
            #pragma unroll
            for (int v = 0; v < 16; ++v) {
                const float d = a0 * bv[3 * v + 0] + a1 * bv[3 * v + 1] + a2 * bv[3 * v + 2];
                const float p = d * c1;
                #pragma unroll
                for (int w = 0; w < 32; ++w)
                    acc[w] = fmaf(p, wp[v * 32 + w], acc[w]);
            }
        }
    }
    { // L2 x L2 (dot over 5) -> W2 (8,8,32), * 1/sqrt(5)
        float bt[40];
        #pragma unroll
        for (int q = 0; q < 10; ++q) {
            const float4 f = *reinterpret_cast<const float4*>(x2 + 80 + 4 * q);
            bt[4 * q + 0] = f.x; bt[4 * q + 1] = f.y;
            bt[4 * q + 2] = f.z; bt[4 * q + 3] = f.w;
        }
        const float c2 = 0.44721359549995794f; // 1/sqrt(5)
        #pragma unroll 2
        for (int u = 0; u < 8; ++u) {
            const float a0 = x1[80 + 5 * u + 0];
            const float a1 = x1[80 + 5 * u + 1];
            const float a2 = x1[80 + 5 * u + 2];
            const float a3 = x1[80 + 5 * u + 3];
            const float a4 = x1[80 + 5 * u + 4];
            const float* __restrict__ wp = W2 + u * 256;
            #pragma unroll
            for (int v = 0; v < 8; ++v) {
                const float d = a0 * bt[5 * v + 0] + a1 * bt[5 * v + 1] + a2 * bt[5 * v + 2]
                              + a3 * bt[5 * v + 3] + a4 * bt[5 * v + 4];
                const float p = d * c2;
                #pragma unroll
                for (int w = 0; w < 32; ++w)
                    acc[w] = fmaf(p, wp[v * 32 + w], acc[w]);
            }
        }
    }

    // ---------------- scale + layernorm ----------------
    const float tp_scale = 0.027277236685610633f; // 1/sqrt(32*32 + 16*16 + 8*8)
    #pragma unroll
    for (int w = 0; w < 32; ++w) acc[w] *= tp_scale;
    float mu = 0.0f;
    #pragma unroll
    for (int w = 0; w < 32; ++w) mu += acc[w];
    mu *= (1.0f / 32.0f);
    float var = 0.0f;
    #pragma unroll
    for (int w = 0; w < 32; ++w) { const float d = acc[w] - mu; var = fmaf(d, d, var); }
    var *= (1.0f / 32.0f);
    const float rstd = rsqrtf(var + 1e-5f);
    #pragma unroll
    for (int w = 0; w < 32; ++w) {
        const float mn = (acc[w] - mu) * rstd * ln_g[w] + ln_b[w];
        scr[w * BS + tid] = mn; // mixednorm -> LDS (h1/emb region dead)
    }

    // ---------------- MLP layer-1: h2 += mn @ mw1[0:32], then silu ----------
    #pragma unroll 2
    for (int i = 0; i < 32; ++i) {
        const float mi = scr[i * BS + tid];
        const float* __restrict__ wp = mw1 + i * 64;
        #pragma unroll
        for (int j = 0; j < 64; ++j) h2[j] = fmaf(mi, wp[j], h2[j]);
    }
    #pragma unroll
    for (int j = 0; j < 64; ++j) {
        const float x = h2[j];
        scr[j * BS + tid] = x / (1.0f + __expf(-x)); // silu(h2) -> LDS
    }

    // ---------------- MLP layer-2 + out -------------------------------------
    float h3[64];
    #pragma unroll
    for (int j = 0; j < 64; ++j) h3[j] = mb2[j];
    #pragma unroll 2
    for (int k = 0; k < 64; ++k) {
        const float hk = scr[k * BS + tid];
        const float* __restrict__ wp = mw2 + k * 64;
        #pragma unroll
        for (int j = 0; j < 64; ++j) h3[j] = fmaf(hk, wp[j], h3[j]);
    }
    float r = ob[0];
    #pragma unroll
    for (int j = 0; j < 64; ++j) {
        const float x = h3[j];
        r = fmaf(silu_f(x), ow[j], r);
    }
    out[e] = r;
}

extern "C" void kernel_launch(void* const* d_in, const int* in_sizes, int n_in,
                              void* d_out, int out_size, void* d_ws, size_t ws_size,
                              hipStream_t stream) {
    const float* nodes      = (const float*)d_in[0];
    const int*   src        = (const int*)  d_in[1];
    const int*   dst        = (const int*)  d_in[2];
    const int*   batch_vec  = (const int*)  d_in[3];
    const float* cell       = (const float*)d_in[4];
    const float* edge_shift = (const float*)d_in[5];
    const float* pos        = (const float*)d_in[6];
    const float* angles     = (const float*)d_in[7];
    const float* cr_min     = (const float*)d_in[8];
    const float* cr_max     = (const float*)d_in[9];
    const float* W0         = (const float*)d_in[10];
    const float* W1         = (const float*)d_in[11];
    const float* W2         = (const float*)d_in[12];
    const float* ln_g       = (const float*)d_in[13];
    const float* ln_b       = (const float*)d_in[14];
    const float* rw1        = (const float*)d_in[15];
    const float* rb1        = (const float*)d_in[16];
    const float* rw2        = (const float*)d_in[17];
    const float* rb2        = (const float*)d_in[18];
    const float* mw1        = (const float*)d_in[19];
    const float* mb1        = (const float*)d_in[20];
    const float* mw2        = (const float*)d_in[21];
    const float* mb2        = (const float*)d_in[22];
    const float* ow         = (const float*)d_in[23];
    const float* ob         = (const float*)d_in[24];
    float* out = (float*)d_out;

    const dim3 grid((NE + BS - 1) / BS);
    const dim3 block(BS);
    hipLaunchKernelGGL(fused_edge_kernel, grid, block, 0, stream,
                       nodes, src, dst, batch_vec, cell, edge_shift, pos,
                       angles, cr_min, cr_max, W0, W1, W2, ln_g, ln_b,
                       rw1, rb1, rw2, rb2, mw1, mb1, mw2, mb2, ow, ob, out);
}

// Round 11
// 509.584 us; speedup vs baseline: 4.7651x; 1.9120x over previous
//
#include <hip/hip_runtime.h>
#include <math.h>

// Problem constants (from reference)
constexpr int NE  = 200000;  // edges (= 64 * 3125 exactly -> no tail handling)
constexpr int ND  = 120;     // node feature dim = 32 + 48 + 40
constexpr int BS  = 128;     // 2 waves per block
constexpr int EPB = 64;      // edges per block (one per lane)

__device__ __forceinline__ float silu_f(float x) { return x / (1.0f + __expf(-x)); }

// Output-split-by-wave: wave 0 computes outputs [0,32), wave 1 [32,64) of every
// 64-wide layer (16/16 for the 32-wide TP). Weight addresses depend only on
// (loop index, wave id); wave id is pinned to an SGPR via readfirstlane so all
// weight loads stay wave-uniform scalar broadcasts (round-5 failure avoided).
// Halves exchanged via 16 KB feature-major LDS (scr[f*64+el], 2-way banks,
// conflict-free). 2x wave parallelism vs round 7, half per-wave serial work.
__global__ __launch_bounds__(BS, 4) void fused_edge_kernel(
    const float* __restrict__ nodes,
    const int*   __restrict__ src,
    const int*   __restrict__ dst,
    const int*   __restrict__ batch_vec,
    const float* __restrict__ cell,
    const float* __restrict__ edge_shift,
    const float* __restrict__ pos,
    const float* __restrict__ angles,
    const float* __restrict__ cr_min,
    const float* __restrict__ cr_max,
    const float* __restrict__ W0,
    const float* __restrict__ W1,
    const float* __restrict__ W2,
    const float* __restrict__ ln_g,
    const float* __restrict__ ln_b,
    const float* __restrict__ rw1,
    const float* __restrict__ rb1,
    const float* __restrict__ rw2,
    const float* __restrict__ rb2,
    const float* __restrict__ mw1,
    const float* __restrict__ mb1,
    const float* __restrict__ mw2,
    const float* __restrict__ mb2,
    const float* __restrict__ ow,
    const float* __restrict__ ob,
    float* __restrict__ out)
{
    __shared__ float scr[64 * EPB];  // 16 KB exactly -> 10 blocks/CU
    const int tid = threadIdx.x;
    const int el  = tid & 63;                                       // edge slot
    const int wv  = __builtin_amdgcn_readfirstlane(tid >> 6);       // 0 or 1 (SGPR)
    const int j32 = wv * 32;   // this wave's offset into 64-wide outputs
    const int w16 = wv * 16;   // this wave's offset into 32-wide TP outputs
    const int e   = blockIdx.x * EPB + el;                          // exact grid

    const int is = src[e];
    const int id = dst[e];
    const float* __restrict__ x1 = nodes + (size_t)is * ND;
    const float* __restrict__ x2 = nodes + (size_t)id * ND;

    // ---------------- geometry: dist (duplicated in both waves) -------------
    const int bg = batch_vec[is];
    const float* C = cell + bg * 9;
    const float sh0 = edge_shift[e * 3 + 0];
    const float sh1 = edge_shift[e * 3 + 1];
    const float sh2 = edge_shift[e * 3 + 2];
    const float rx = pos[id * 3 + 0] - pos[is * 3 + 0] + sh0 * C[0] + sh1 * C[3] + sh2 * C[6];
    const float ry = pos[id * 3 + 1] - pos[is * 3 + 1] + sh0 * C[1] + sh1 * C[4] + sh2 * C[7];
    const float rz = pos[id * 3 + 2] - pos[is * 3 + 2] + sh0 * C[2] + sh1 * C[5] + sh2 * C[8];
    const float dist = sqrtf(rx * rx + ry * ry + rz * rz);

    // ---------------- P1: radial layer 1 (this wave's 32 of 64) -------------
    {
        float h1h[32];
        #pragma unroll
        for (int j = 0; j < 32; ++j) h1h[j] = rb1[j32 + j];
        #pragma unroll 2
        for (int i = 0; i < 64; ++i) {
            const float dd = dist - (5.0f / 63.0f) * (float)i;
            const float r = __expf(-10.0f * dd * dd);
            const float* __restrict__ wp = rw1 + i * 64 + j32;
            #pragma unroll
            for (int j = 0; j < 32; ++j) h1h[j] = fmaf(r, wp[j], h1h[j]);
        }
        #pragma unroll
        for (int j = 0; j < 32; ++j) scr[(j32 + j) * EPB + el] = silu_f(h1h[j]);
    }
    __syncthreads();  // h1 rows complete

    // ---------------- P2: radial layer 2 (this wave's 32) -------------------
    float embh[32];
    #pragma unroll
    for (int j = 0; j < 32; ++j) embh[j] = rb2[j32 + j];
    #pragma unroll 2
    for (int k = 0; k < 64; ++k) {
        const float hk = scr[k * EPB + el];
        const float* __restrict__ wp = rw2 + k * 64 + j32;
        #pragma unroll
        for (int j = 0; j < 32; ++j) embh[j] = fmaf(hk, wp[j], embh[j]);
    }
    __syncthreads();  // all h1 reads done (WAR)
    #pragma unroll
    for (int j = 0; j < 32; ++j) scr[(j32 + j) * EPB + el] = embh[j];
    __syncthreads();  // emb rows complete

    // ---------------- P3: mlp1 partial: h2h = mb1 + emb@mw1[32:96] + scalars -
    float h2h[32];
    #pragma unroll
    for (int j = 0; j < 32; ++j) h2h[j] = mb1[j32 + j];
    #pragma unroll 2
    for (int i = 0; i < 64; ++i) {
        const float ei = scr[i * EPB + el];
        const float* __restrict__ wp = mw1 + (32 + i) * 64 + j32;
        #pragma unroll
        for (int j = 0; j < 32; ++j) h2h[j] = fmaf(ei, wp[j], h2h[j]);
    }
    {
        const float a  = angles[e];
        const float cm = cr_min[e];
        const float cx = cr_max[e];
        const float* __restrict__ wa = mw1 + 96 * 64 + j32;
        const float* __restrict__ wb = mw1 + 97 * 64 + j32;
        const float* __restrict__ wc = mw1 + 98 * 64 + j32;
        #pragma unroll
        for (int j = 0; j < 32; ++j)
            h2h[j] += a * wa[j] + cm * wb[j] + cx * wc[j];
    }
    __syncthreads();  // all emb reads done (WAR before acc exchange)

    // ---------------- P4: tensor product (this wave's 16 of 32) -------------
    float acc[16];
    #pragma unroll
    for (int wl = 0; wl < 16; ++wl) acc[wl] = 0.0f;

    { // L0 x L0 -> W0 (32,32,32)
        float b0[32];
        #pragma unroll
        for (int q = 0; q < 8; ++q) {
            const float4 f = *reinterpret_cast<const float4*>(x2 + 4 * q);
            b0[4 * q + 0] = f.x; b0[4 * q + 1] = f.y;
            b0[4 * q + 2] = f.z; b0[4 * q + 3] = f.w;
        }
        #pragma unroll 2
        for (int u = 0; u < 32; ++u) {
            const float a = x1[u];
            const float* __restrict__ wp = W0 + u * 1024 + w16;
            #pragma unroll
            for (int v = 0; v < 32; ++v) {
                const float p = a * b0[v];
                #pragma unroll
                for (int wl = 0; wl < 16; ++wl)
                    acc[wl] = fmaf(p, wp[v * 32 + wl], acc[wl]);
            }
        }
    }
    { // L1 x L1 (dot over 3) -> W1 (16,16,32), * 1/sqrt(3)
        float bv[48];
        #pragma unroll
        for (int q = 0; q < 12; ++q) {
            const float4 f = *reinterpret_cast<const float4*>(x2 + 32 + 4 * q);
            bv[4 * q + 0] = f.x; bv[4 * q + 1] = f.y;
            bv[4 * q + 2] = f.z; bv[4 * q + 3] = f.w;
        }
        const float c1 = 0.57735026918962576f; // 1/sqrt(3)
        #pragma unroll 2
        for (int u = 0; u < 16; ++u) {
            const float a0 = x1[32 + 3 * u + 0];
            const float a1 = x1[32 + 3 * u + 1];
            const float a2 = x1[32 + 3 * u + 2];
            const float* __restrict__ wp = W1 + u * 512 + w16;
            #pragma unroll
            for (int v = 0; v < 16; ++v) {
                const float d = a0 * bv[3 * v + 0] + a1 * bv[3 * v + 1] + a2 * bv[3 * v + 2];
                const float p = d * c1;
                #pragma unroll
                for (int wl = 0; wl < 16; ++wl)
                    acc[wl] = fmaf(p, wp[v * 32 + wl], acc[wl]);
            }
        }
    }
    { // L2 x L2 (dot over 5) -> W2 (8,8,32), * 1/sqrt(5)
        float bt[40];
        #pragma unroll
        for (int q = 0; q < 10; ++q) {
            const float4 f = *reinterpret_cast<const float4*>(x2 + 80 + 4 * q);
            bt[4 * q + 0] = f.x; bt[4 * q + 1] = f.y;
            bt[4 * q + 2] = f.z; bt[4 * q + 3] = f.w;
        }
        const float c2 = 0.44721359549995794f; // 1/sqrt(5)
        #pragma unroll 2
        for (int u = 0; u < 8; ++u) {
            const float a0 = x1[80 + 5 * u + 0];
            const float a1 = x1[80 + 5 * u + 1];
            const float a2 = x1[80 + 5 * u + 2];
            const float a3 = x1[80 + 5 * u + 3];
            const float a4 = x1[80 + 5 * u + 4];
            const float* __restrict__ wp = W2 + u * 256 + w16;
            #pragma unroll
            for (int v = 0; v < 8; ++v) {
                const float d = a0 * bt[5 * v + 0] + a1 * bt[5 * v + 1] + a2 * bt[5 * v + 2]
                              + a3 * bt[5 * v + 3] + a4 * bt[5 * v + 4];
                const float p = d * c2;
                #pragma unroll
                for (int wl = 0; wl < 16; ++wl)
                    acc[wl] = fmaf(p, wp[v * 32 + wl], acc[wl]);
            }
        }
    }

    // exchange acc halves (rows 0..31 of scr)
    const float tp_scale = 0.027277236685610633f; // 1/sqrt(32*32 + 16*16 + 8*8)
    #pragma unroll
    for (int wl = 0; wl < 16; ++wl) scr[(w16 + wl) * EPB + el] = acc[wl] * tp_scale;
    __syncthreads();  // acc rows complete

    // ---------------- layernorm (full 32 in registers, both waves) ----------
    float a32[32];
    #pragma unroll
    for (int ww = 0; ww < 32; ++ww) a32[ww] = scr[ww * EPB + el];
    __syncthreads();  // acc reads done (WAR before silu(h2) write)

    float mu = 0.0f;
    #pragma unroll
    for (int ww = 0; ww < 32; ++ww) mu += a32[ww];
    mu *= (1.0f / 32.0f);
    float var = 0.0f;
    #pragma unroll
    for (int ww = 0; ww < 32; ++ww) { const float d = a32[ww] - mu; var = fmaf(d, d, var); }
    var *= (1.0f / 32.0f);
    const float rstd = rsqrtf(var + 1e-5f);
    float mn[32];
    #pragma unroll
    for (int ww = 0; ww < 32; ++ww)
        mn[ww] = (a32[ww] - mu) * rstd * ln_g[ww] + ln_b[ww];

    // ---------------- P5: h2h += mn @ mw1[0:32] (mn static-indexed), silu ---
    #pragma unroll
    for (int i = 0; i < 32; ++i) {
        const float mi = mn[i];
        const float* __restrict__ wp = mw1 + i * 64 + j32;
        #pragma unroll
        for (int j = 0; j < 32; ++j) h2h[j] = fmaf(mi, wp[j], h2h[j]);
    }
    #pragma unroll
    for (int j = 0; j < 32; ++j) scr[(j32 + j) * EPB + el] = silu_f(h2h[j]);
    __syncthreads();  // silu(h2) rows complete

    // ---------------- P6: mlp2 (this wave's 32) + output dot ----------------
    float h3h[32];
    #pragma unroll
    for (int j = 0; j < 32; ++j) h3h[j] = mb2[j32 + j];
    #pragma unroll 2
    for (int k = 0; k < 64; ++k) {
        const float hk = scr[k * EPB + el];
        const float* __restrict__ wp = mw2 + k * 64 + j32;
        #pragma unroll
        for (int j = 0; j < 32; ++j) h3h[j] = fmaf(hk, wp[j], h3h[j]);
    }
    float r = 0.0f;
    #pragma unroll
    for (int j = 0; j < 32; ++j) r = fmaf(silu_f(h3h[j]), ow[j32 + j], r);

    __syncthreads();  // all silu(h2) reads done (WAR: reuse scr rows 0..1)
    scr[wv * EPB + el] = r;  // partial dot per wave
    __syncthreads();
    if (wv == 0) out[e] = scr[el] + scr[EPB + el] + ob[0];
}

extern "C" void kernel_launch(void* const* d_in, const int* in_sizes, int n_in,
                              void* d_out, int out_size, void* d_ws, size_t ws_size,
                              hipStream_t stream) {
    const float* nodes      = (const float*)d_in[0];
    const int*   src        = (const int*)  d_in[1];
    const int*   dst        = (const int*)  d_in[2];
    const int*   batch_vec  = (const int*)  d_in[3];
    const float* cell       = (const float*)d_in[4];
    const float* edge_shift = (const float*)d_in[5];
    const float* pos        = (const float*)d_in[6];
    const float* angles     = (const float*)d_in[7];
    const float* cr_min     = (const float*)d_in[8];
    const float* cr_max     = (const float*)d_in[9];
    const float* W0         = (const float*)d_in[10];
    const float* W1         = (const float*)d_in[11];
    const float* W2         = (const float*)d_in[12];
    const float* ln_g       = (const float*)d_in[13];
    const float* ln_b       = (const float*)d_in[14];
    const float* rw1        = (const float*)d_in[15];
    const float* rb1        = (const float*)d_in[16];
    const float* rw2        = (const float*)d_in[17];
    const float* rb2        = (const float*)d_in[18];
    const float* mw1        = (const float*)d_in[19];
    const float* mb1        = (const float*)d_in[20];
    const float* mw2        = (const float*)d_in[21];
    const float* mb2        = (const float*)d_in[22];
    const float* ow         = (const float*)d_in[23];
    const float* ob         = (const float*)d_in[24];
    float* out = (float*)d_out;

    const dim3 grid(NE / EPB);   // 3125 blocks, exact
    const dim3 block(BS);
    hipLaunchKernelGGL(fused_edge_kernel, grid, block, 0, stream,
                       nodes, src, dst, batch_vec, cell, edge_shift, pos,
                       angles, cr_min, cr_max, W0, W1, W2, ln_g, ln_b,
                       rw1, rb1, rw2, rb2, mw1, mb1, mw2, mb2, ow, ob, out);
}